// Round 6
// baseline (396096.875 us; speedup 1.0000x reference)
//
#include <hip/hip_runtime.h>
#include <hip/hip_cooperative_groups.h>

namespace cg = cooperative_groups;

#define H      2048
#define NIN    512
#define TH     (3 * H)
#define SEQLEN 2048
#define KSP    204          // int(2048 * 0.1)
#define NBLK   256
#define NTHR   512
#define NWAVES (NBLK * (NTHR / 64))

static_assert(NWAVES == H, "one wave per hidden element");

struct Params {
    const float* seq;
    const float* eWih0; const float* eWih1; const float* eWhh;
    const float* ebih;  const float* ebhh;
    const float* dWih0; const float* dWih1; const float* dWhh;
    const float* dbih;  const float* dbhh;
    const float* dWout; const float* dbout;
    float* out;   // [2047*512 + 1]
    float* ws;
};

__device__ __forceinline__ float wave_reduce_f(float v) {
#pragma unroll
    for (int m = 32; m >= 1; m >>= 1) v += __shfl_xor(v, m, 64);
    return v;
}

// One GRU output element j, computed by one full wave. float4 lanes:
// lane reads 16B at element offset 4*(lane + 64*k); rows are 16B-aligned
// (xdim multiple of 4, base hipMalloc'd).
// PyTorch gate order (r, z, n):
//   r = sigm(Wih[j]·x + bih[j] + Whh[j]·h + bhh[j])
//   z = sigm(row H+j ...)
//   n = tanh(Wih[2H+j]·x + bih[2H+j] + r*(Whh[2H+j]·h + bhh[2H+j]))
//   h' = (1-z)*n + z*h
template <int XDIM>
__device__ __forceinline__ void gru_phase(int j, int lane,
    const float* __restrict__ Wih, const float* __restrict__ Whh,
    const float* __restrict__ bih, const float* __restrict__ bhh,
    const float* __restrict__ x,
    const float* __restrict__ hcur, float* __restrict__ hnxt)
{
    const float4* wir = (const float4*)(Wih + (size_t)j * XDIM);
    const float4* wiz = (const float4*)(Wih + (size_t)(H + j) * XDIM);
    const float4* win = (const float4*)(Wih + (size_t)(2 * H + j) * XDIM);
    const float4* whr = (const float4*)(Whh + (size_t)j * H);
    const float4* whz = (const float4*)(Whh + (size_t)(H + j) * H);
    const float4* whn = (const float4*)(Whh + (size_t)(2 * H + j) * H);
    const float4* x4  = (const float4*)x;
    const float4* h4  = (const float4*)hcur;

    float air = 0.f, aiz = 0.f, ain = 0.f;
#pragma unroll
    for (int k = 0; k < XDIM / 256; ++k) {
        int i = lane + 64 * k;
        float4 xv = x4[i];
        float4 a = wir[i], b = wiz[i], c = win[i];
        air = fmaf(a.x, xv.x, air); air = fmaf(a.y, xv.y, air);
        air = fmaf(a.z, xv.z, air); air = fmaf(a.w, xv.w, air);
        aiz = fmaf(b.x, xv.x, aiz); aiz = fmaf(b.y, xv.y, aiz);
        aiz = fmaf(b.z, xv.z, aiz); aiz = fmaf(b.w, xv.w, aiz);
        ain = fmaf(c.x, xv.x, ain); ain = fmaf(c.y, xv.y, ain);
        ain = fmaf(c.z, xv.z, ain); ain = fmaf(c.w, xv.w, ain);
    }
    float ahr = 0.f, ahz = 0.f, ahn = 0.f;
#pragma unroll
    for (int k = 0; k < H / 256; ++k) {
        int i = lane + 64 * k;
        float4 hv = h4[i];
        float4 a = whr[i], b = whz[i], c = whn[i];
        ahr = fmaf(a.x, hv.x, ahr); ahr = fmaf(a.y, hv.y, ahr);
        ahr = fmaf(a.z, hv.z, ahr); ahr = fmaf(a.w, hv.w, ahr);
        ahz = fmaf(b.x, hv.x, ahz); ahz = fmaf(b.y, hv.y, ahz);
        ahz = fmaf(b.z, hv.z, ahz); ahz = fmaf(b.w, hv.w, ahz);
        ahn = fmaf(c.x, hv.x, ahn); ahn = fmaf(c.y, hv.y, ahn);
        ahn = fmaf(c.z, hv.z, ahn); ahn = fmaf(c.w, hv.w, ahn);
    }
    float sr   = wave_reduce_f(air + ahr);   // gi_r + gh_r
    float sz   = wave_reduce_f(aiz + ahz);   // gi_z + gh_z
    float sin_ = wave_reduce_f(ain);         // gi_n (bias added below)
    float shn  = wave_reduce_f(ahn);         // gh_n

    if (lane == 0) {
        float r = 1.f / (1.f + expf(-(sr + bih[j] + bhh[j])));
        float z = 1.f / (1.f + expf(-(sz + bih[H + j] + bhh[H + j])));
        float n = tanhf(sin_ + bih[2 * H + j] + r * (shn + bhh[2 * H + j]));
        hnxt[j] = (1.f - z) * n + z * hcur[j];
    }
}

__global__ void __launch_bounds__(NTHR)
seqae_kernel(Params p)
{
    cg::grid_group grid = cg::this_grid();
    const int lane = threadIdx.x & 63;
    const int wid  = blockIdx.x * (NTHR / 64) + (threadIdx.x >> 6);

    float* loss = p.ws;
    float* h0a  = p.ws + 64;
    float* h0b  = h0a + H;
    float* h1a  = h0b + H;
    float* h1b  = h1a + H;

    // ---- init: zero loss + initial hidden states (ws is poisoned 0xAA) ----
    {
        int gtid = blockIdx.x * NTHR + threadIdx.x;
        if (gtid == 0) *loss = 0.f;
        for (int i = gtid; i < H; i += NBLK * NTHR) { h0a[i] = 0.f; h1a[i] = 0.f; }
    }
    grid.sync();

    const float* ebih0 = p.ebih;        const float* ebih1 = p.ebih + TH;
    const float* ebhh0 = p.ebhh;        const float* ebhh1 = p.ebhh + TH;
    const float* eWhh0 = p.eWhh;        const float* eWhh1 = p.eWhh + (size_t)TH * H;

    float* h0c = h0a; float* h0n = h0b;
    float* h1c = h1a; float* h1n = h1b;

    // ---- encoder: 2048 steps x 2 layers ----
    for (int t = 0; t < SEQLEN; ++t) {
        const float* x = p.seq + (size_t)t * NIN;
        gru_phase<NIN>(wid, lane, p.eWih0, eWhh0, ebih0, ebhh0, x, h0c, h0n);
        grid.sync();
        gru_phase<H>(wid, lane, p.eWih1, eWhh1, ebih1, ebhh1, h0n, h1c, h1n);
        grid.sync();
        float* tmp;
        tmp = h0c; h0c = h0n; h0n = tmp;
        tmp = h1c; h1c = h1n; h1n = tmp;
    }

    // ---- exact top-k (k=204) mask on final h1, lax.top_k tie-break ----
    {
        int j = wid;
        float vj = h1c[j];
        int cnt = 0;
        for (int i = lane; i < H; i += 64) {
            float vi = h1c[i];
            cnt += (vi > vj) || (vi == vj && i < j);
        }
#pragma unroll
        for (int m = 32; m >= 1; m >>= 1) cnt += __shfl_xor(cnt, m, 64);
        if (lane == 0) h1n[j] = (cnt < KSP) ? vj : 0.f;
    }
    grid.sync();
    { float* tmp = h1c; h1c = h1n; h1n = tmp; }   // h1c = masked state

    const float* dbih0 = p.dbih;        const float* dbih1 = p.dbih + TH;
    const float* dbhh0 = p.dbhh;        const float* dbhh1 = p.dbhh + TH;
    const float* dWhh0 = p.dWhh;        const float* dWhh1 = p.dWhh + (size_t)TH * H;

    // ---- decoder: 2047 autoregressive steps ----
    float lsum = 0.f;   // per-wave loss accumulator (waves 0..511, lane 0)
    for (int t = 0; t < SEQLEN - 1; ++t) {
        const float* x = (t == 0) ? (p.seq + (size_t)(SEQLEN - 1) * NIN)
                                  : (p.out + (size_t)(t - 1) * NIN);
        gru_phase<NIN>(wid, lane, p.dWih0, dWhh0, dbih0, dbhh0, x, h0c, h0n);
        grid.sync();
        gru_phase<H>(wid, lane, p.dWih1, dWhh1, dbih1, dbhh1, h0n, h1c, h1n);
        grid.sync();
        // output linear + step loss; h1n holds the new h1
        if (wid < NIN) {
            int j = wid;
            const float4* wo = (const float4*)(p.dWout + (size_t)j * H);
            const float4* h4 = (const float4*)h1n;
            float a = 0.f;
#pragma unroll
            for (int k = 0; k < H / 256; ++k) {
                int i = lane + 64 * k;
                float4 w = wo[i]; float4 hv = h4[i];
                a = fmaf(w.x, hv.x, a); a = fmaf(w.y, hv.y, a);
                a = fmaf(w.z, hv.z, a); a = fmaf(w.w, hv.w, a);
            }
            a = wave_reduce_f(a);
            if (lane == 0) {
                float o = a + p.dbout[j];
                p.out[(size_t)t * NIN + j] = o;
                float tg = p.seq[(size_t)(SEQLEN - 2 - t) * NIN + j];
                float d = o - tg;
                lsum = fmaf(d, d, lsum);
            }
        }
        grid.sync();
        float* tmp;
        tmp = h0c; h0c = h0n; h0n = tmp;
        tmp = h1c; h1c = h1n; h1n = tmp;
    }

    if (wid < NIN && lane == 0) atomicAdd(loss, lsum);
    grid.sync();
    if (blockIdx.x == 0 && threadIdx.x == 0) {
        p.out[(size_t)(SEQLEN - 1) * NIN] = (*loss) * (1.f / ((float)NIN * (float)SEQLEN));
    }
}

extern "C" void kernel_launch(void* const* d_in, const int* in_sizes, int n_in,
                              void* d_out, int out_size, void* d_ws, size_t ws_size,
                              hipStream_t stream)
{
    Params p;
    p.seq   = (const float*)d_in[0];
    p.eWih0 = (const float*)d_in[1];
    p.eWih1 = (const float*)d_in[2];
    p.eWhh  = (const float*)d_in[3];
    p.ebih  = (const float*)d_in[4];
    p.ebhh  = (const float*)d_in[5];
    p.dWih0 = (const float*)d_in[6];
    p.dWih1 = (const float*)d_in[7];
    p.dWhh  = (const float*)d_in[8];
    p.dbih  = (const float*)d_in[9];
    p.dbhh  = (const float*)d_in[10];
    p.dWout = (const float*)d_in[11];
    p.dbout = (const float*)d_in[12];
    p.out = (float*)d_out;
    p.ws  = (float*)d_ws;

    void* args[] = { &p };
    (void)hipLaunchCooperativeKernel((void*)seqae_kernel, dim3(NBLK), dim3(NTHR),
                                     args, 0, stream);
}

// Round 8
// 370632.397 us; speedup vs baseline: 1.0687x; 1.0687x over previous
//
#include <hip/hip_runtime.h>
#include <hip/hip_fp16.h>
#include <hip/hip_cooperative_groups.h>

namespace cg = cooperative_groups;

#define H      2048
#define NIN    512
#define TH     (3 * H)
#define SEQLEN 2048
#define KSP    204          // int(2048 * 0.1)
#define NBLK   256
#define NTHR   512

typedef unsigned int uint32;

// ---------- packed fp16 weight segments in d_ws ----------
// layout per segment: [elem j][row r][u = kk*2+p2][lane]  (uint32 = 2 fp16)
// element cols per uint: c0 = 256*kk + 4*lane + 2*p2  -> (c0, c0+1)
constexpr long O_EA = 0;                       // enc Wih0  (xdim 512,  NU=4)
constexpr long O_EB = O_EA + 1572864;          // enc Whh0  (xdim 2048, NU=16)
constexpr long O_EC = O_EB + 6291456;          // enc Wih1
constexpr long O_ED = O_EC + 6291456;          // enc Whh1
constexpr long O_DA = O_ED + 6291456;          // dec Wih0
constexpr long O_DB = O_DA + 1572864;          // dec Whh0
constexpr long O_DC = O_DB + 6291456;          // dec Wih1
constexpr long O_DD = O_DC + 6291456;          // dec Whh1
constexpr long O_WO = O_DD + 6291456;          // Wout (512 rows, NU=16)
constexpr long U_TOTAL = O_WO + 524288;        // 41,418,752 uints = 158 MiB
constexpr size_t WS_STATE_BYTES = 65536;

struct Params {
    const float* seq;
    const float* eWih0; const float* eWih1; const float* eWhh;
    const float* ebih;  const float* ebhh;
    const float* dWih0; const float* dWih1; const float* dWhh;
    const float* dbih;  const float* dbhh;
    const float* dWout; const float* dbout;
    float* out;   // [2047*512 + 1]
    float* ws;
};

__device__ __forceinline__ float wave_reduce_f(float v) {
#pragma unroll
    for (int m = 32; m >= 1; m >>= 1) v += __shfl_xor(v, m, 64);
    return v;
}

__device__ __forceinline__ float sigmoidf_(float v) { return 1.f / (1.f + expf(-v)); }

__device__ __forceinline__ float2 h2f(uint32 u) {
    __half2 h = *reinterpret_cast<__half2*>(&u);
    return __half22float2(h);
}

// ---------- fp32 -> packed fp16 prep ----------
__global__ void pack_kernel(const float* __restrict__ src, uint32* __restrict__ dst,
                            int total, int xdim, int nrows)
{
    int KK = xdim / 256;
    for (int i = blockIdx.x * blockDim.x + threadIdx.x; i < total;
         i += gridDim.x * blockDim.x) {
        int l = i & 63;
        int rest = i >> 6;
        int p2 = rest & 1; rest >>= 1;
        int kk = rest % KK; rest /= KK;
        int r  = rest % nrows; rest /= nrows;
        int j  = rest;
        int c0 = 256 * kk + 4 * l + 2 * p2;
        const float* row = src + ((size_t)r * H + j) * xdim;
        unsigned short b0 = __half_as_ushort(__float2half_rn(row[c0]));
        unsigned short b1 = __half_as_ushort(__float2half_rn(row[c0 + 1]));
        dst[i] = ((uint32)b1 << 16) | b0;
    }
}

// ---------- register loaders ----------
template <int NU>
__device__ __forceinline__ void load_seg3(uint32 (&dst)[3][NU], const uint32* seg,
                                          int j, int lane)
{
#pragma unroll
    for (int r = 0; r < 3; ++r)
#pragma unroll
        for (int u = 0; u < NU; ++u)
            dst[r][u] = seg[((size_t)(j * 3 + r) * NU + u) * 64 + lane];
}

__device__ __forceinline__ void load_seg1(uint32 (&dst)[16], const uint32* seg,
                                          int j, int lane)
{
#pragma unroll
    for (int u = 0; u < 16; ++u)
        dst[u] = seg[((size_t)j * 16 + u) * 64 + lane];
}

// ---------- dot of 3 register-resident fp16 rows with a global fp32 vector ----------
template <int NU>
__device__ __forceinline__ void dot3h(const uint32 (&w)[3][NU],
                                      const float* __restrict__ vec, int lane,
                                      float acc[3])
{
#pragma unroll
    for (int kk = 0; kk < NU / 2; ++kk) {
        float4 v = ((const float4*)vec)[kk * 64 + lane];
#pragma unroll
        for (int r = 0; r < 3; ++r) {
            float2 lo = h2f(w[r][2 * kk]);
            float2 hi = h2f(w[r][2 * kk + 1]);
            acc[r] = fmaf(lo.x, v.x, acc[r]);
            acc[r] = fmaf(lo.y, v.y, acc[r]);
            acc[r] = fmaf(hi.x, v.z, acc[r]);
            acc[r] = fmaf(hi.y, v.w, acc[r]);
        }
    }
}

// GRU cell with register-resident weights. Returns h'[j] (same value in all lanes).
template <int NUX>
__device__ __forceinline__ float gru_cell_reg(int j, int lane,
    const uint32 (&wi)[3][NUX], const uint32 (&wh)[3][16],
    const float* __restrict__ x, const float* __restrict__ h,
    float bir, float biz, float bin, float bhr, float bhz, float bhn)
{
    float ai[3] = {0.f, 0.f, 0.f}, ah[3] = {0.f, 0.f, 0.f};
    dot3h<NUX>(wi, x, lane, ai);
    dot3h<16>(wh, h, lane, ah);
    float hj  = h[j];                      // wave-uniform
    float sr  = wave_reduce_f(ai[0] + ah[0]);
    float sz  = wave_reduce_f(ai[1] + ah[1]);
    float sn  = wave_reduce_f(ai[2]);
    float shn = wave_reduce_f(ah[2]);
    float r = sigmoidf_(sr + bir + bhr);
    float z = sigmoidf_(sz + biz + bhz);
    float n = tanhf(sn + bin + r * (shn + bhn));
    return (1.f - z) * n + z * hj;
}

// ---------- persistent kernel, register-resident fp16 weights ----------
__global__ void __launch_bounds__(NTHR, 2)
seqae_reg_kernel(Params p)
{
    cg::grid_group grid = cg::this_grid();
    const int lane = threadIdx.x & 63;
    const int j    = blockIdx.x * (NTHR / 64) + (threadIdx.x >> 6);   // 0..2047

    float* loss = p.ws;
    float* h0b[2] = { p.ws + 64, p.ws + 64 + H };
    float* h1b[2] = { p.ws + 64 + 2 * H, p.ws + 64 + 3 * H };
    const uint32* U = (const uint32*)((const char*)p.ws + WS_STATE_BYTES);

    {   // init (ws poisoned 0xAA each call)
        int gtid = blockIdx.x * NTHR + threadIdx.x;
        if (gtid == 0) *loss = 0.f;
        for (int i = gtid; i < H; i += NBLK * NTHR) { h0b[0][i] = 0.f; h1b[0][i] = 0.f; }
    }
    grid.sync();

    uint32 wa[3][4], wb[3][16], wc[3][16], wd[3][16];
    load_seg3<4>(wa, U + O_EA, j, lane);
    load_seg3<16>(wb, U + O_EB, j, lane);
    load_seg3<16>(wc, U + O_EC, j, lane);
    load_seg3<16>(wd, U + O_ED, j, lane);

    float eb[12];
    {
        const float* bi0 = p.ebih;      const float* bi1 = p.ebih + TH;
        const float* bh0 = p.ebhh;      const float* bh1 = p.ebhh + TH;
        eb[0] = bi0[j]; eb[1] = bi0[H + j]; eb[2] = bi0[2 * H + j];
        eb[3] = bh0[j]; eb[4] = bh0[H + j]; eb[5] = bh0[2 * H + j];
        eb[6] = bi1[j]; eb[7] = bi1[H + j]; eb[8] = bi1[2 * H + j];
        eb[9] = bh1[j]; eb[10] = bh1[H + j]; eb[11] = bh1[2 * H + j];
    }

    int c0 = 0, c1 = 0;

    // ---- encoder, software-pipelined: phase p computes layer0(t=p) || layer1(t=p-1)
    for (int ph = 0; ph <= SEQLEN; ++ph) {
        const float* h0old = h0b[c0];
        float h0v = 0.f, h1v = 0.f;
        if (ph < SEQLEN)
            h0v = gru_cell_reg<4>(j, lane, wa, wb, p.seq + (size_t)ph * NIN, h0old,
                                  eb[0], eb[1], eb[2], eb[3], eb[4], eb[5]);
        if (ph >= 1)
            h1v = gru_cell_reg<16>(j, lane, wc, wd, h0old, h1b[c1],
                                   eb[6], eb[7], eb[8], eb[9], eb[10], eb[11]);
        if (lane == 0) {
            if (ph < SEQLEN) h0b[c0 ^ 1][j] = h0v;
            if (ph >= 1)     h1b[c1 ^ 1][j] = h1v;
        }
        grid.sync();
        if (ph < SEQLEN) c0 ^= 1;
        if (ph >= 1)     c1 ^= 1;
    }

    // ---- exact top-k (k=204) on final h1, lax.top_k tie-break ----
    {
        const float* hs = h1b[c1];
        float vj = hs[j];
        int cnt = 0;
        for (int i = lane; i < H; i += 64) {
            float vi = hs[i];
            cnt += (vi > vj) || (vi == vj && i < j);
        }
#pragma unroll
        for (int m = 32; m >= 1; m >>= 1) cnt += __shfl_xor(cnt, m, 64);
        if (lane == 0) h1b[c1 ^ 1][j] = (cnt < KSP) ? vj : 0.f;
    }
    grid.sync();
    c1 ^= 1;

    // ---- decoder weights into the same registers ----
    load_seg3<4>(wa, U + O_DA, j, lane);
    load_seg3<16>(wb, U + O_DB, j, lane);
    load_seg3<16>(wc, U + O_DC, j, lane);
    load_seg3<16>(wd, U + O_DD, j, lane);
    uint32 wo[16];
    load_seg1(wo, U + O_WO, j & (NIN - 1), lane);

    float db[12], boutj;
    {
        const float* bi0 = p.dbih;      const float* bi1 = p.dbih + TH;
        const float* bh0 = p.dbhh;      const float* bh1 = p.dbhh + TH;
        db[0] = bi0[j]; db[1] = bi0[H + j]; db[2] = bi0[2 * H + j];
        db[3] = bh0[j]; db[4] = bh0[H + j]; db[5] = bh0[2 * H + j];
        db[6] = bi1[j]; db[7] = bi1[H + j]; db[8] = bi1[2 * H + j];
        db[9] = bh1[j]; db[10] = bh1[H + j]; db[11] = bh1[2 * H + j];
        boutj = p.dbout[j & (NIN - 1)];
    }

    // ---- decoder: 2047 steps x 3 phases ----
    float lsum = 0.f;
    for (int t = 0; t < SEQLEN - 1; ++t) {
        const float* x = (t == 0) ? (p.seq + (size_t)(SEQLEN - 1) * NIN)
                                  : (p.out + (size_t)(t - 1) * NIN);
        float h0v = gru_cell_reg<4>(j, lane, wa, wb, x, h0b[c0],
                                    db[0], db[1], db[2], db[3], db[4], db[5]);
        if (lane == 0) h0b[c0 ^ 1][j] = h0v;
        grid.sync(); c0 ^= 1;

        float h1v = gru_cell_reg<16>(j, lane, wc, wd, h0b[c0], h1b[c1],
                                     db[6], db[7], db[8], db[9], db[10], db[11]);
        if (lane == 0) h1b[c1 ^ 1][j] = h1v;
        grid.sync(); c1 ^= 1;

        if (j < NIN) {
            const float* h1n = h1b[c1];
            float a = 0.f;
#pragma unroll
            for (int kk = 0; kk < 8; ++kk) {
                float4 v = ((const float4*)h1n)[kk * 64 + lane];
                float2 lo = h2f(wo[2 * kk]);
                float2 hi = h2f(wo[2 * kk + 1]);
                a = fmaf(lo.x, v.x, a); a = fmaf(lo.y, v.y, a);
                a = fmaf(hi.x, v.z, a); a = fmaf(hi.y, v.w, a);
            }
            a = wave_reduce_f(a);
            float o = a + boutj;
            if (lane == 0) p.out[(size_t)t * NIN + j] = o;
            float tg = p.seq[(size_t)(SEQLEN - 2 - t) * NIN + j];
            float d = o - tg;
            lsum = fmaf(d, d, lsum);
        }
        grid.sync();
    }

    if (j < NIN && lane == 0) atomicAdd(loss, lsum);
    grid.sync();
    if (blockIdx.x == 0 && threadIdx.x == 0)
        p.out[(size_t)(SEQLEN - 1) * NIN] = (*loss) * (1.f / ((float)NIN * (float)SEQLEN));
}

// ======================================================================
// Fallback (Round-6 kernel, fp32 streaming) — used if ws_size too small.
// ======================================================================
template <int XDIM>
__device__ __forceinline__ void gru_phase_fb(int j, int lane,
    const float* __restrict__ Wih, const float* __restrict__ Whh,
    const float* __restrict__ bih, const float* __restrict__ bhh,
    const float* __restrict__ x,
    const float* __restrict__ hcur, float* __restrict__ hnxt)
{
    const float4* wir = (const float4*)(Wih + (size_t)j * XDIM);
    const float4* wiz = (const float4*)(Wih + (size_t)(H + j) * XDIM);
    const float4* win = (const float4*)(Wih + (size_t)(2 * H + j) * XDIM);
    const float4* whr = (const float4*)(Whh + (size_t)j * H);
    const float4* whz = (const float4*)(Whh + (size_t)(H + j) * H);
    const float4* whn = (const float4*)(Whh + (size_t)(2 * H + j) * H);
    const float4* x4  = (const float4*)x;
    const float4* h4  = (const float4*)hcur;

    float air = 0.f, aiz = 0.f, ain = 0.f;
#pragma unroll
    for (int k = 0; k < XDIM / 256; ++k) {
        int i = lane + 64 * k;
        float4 xv = x4[i];
        float4 a = wir[i], b = wiz[i], c = win[i];
        air = fmaf(a.x, xv.x, air); air = fmaf(a.y, xv.y, air);
        air = fmaf(a.z, xv.z, air); air = fmaf(a.w, xv.w, air);
        aiz = fmaf(b.x, xv.x, aiz); aiz = fmaf(b.y, xv.y, aiz);
        aiz = fmaf(b.z, xv.z, aiz); aiz = fmaf(b.w, xv.w, aiz);
        ain = fmaf(c.x, xv.x, ain); ain = fmaf(c.y, xv.y, ain);
        ain = fmaf(c.z, xv.z, ain); ain = fmaf(c.w, xv.w, ain);
    }
    float ahr = 0.f, ahz = 0.f, ahn = 0.f;
#pragma unroll
    for (int k = 0; k < H / 256; ++k) {
        int i = lane + 64 * k;
        float4 hv = h4[i];
        float4 a = whr[i], b = whz[i], c = whn[i];
        ahr = fmaf(a.x, hv.x, ahr); ahr = fmaf(a.y, hv.y, ahr);
        ahr = fmaf(a.z, hv.z, ahr); ahr = fmaf(a.w, hv.w, ahr);
        ahz = fmaf(b.x, hv.x, ahz); ahz = fmaf(b.y, hv.y, ahz);
        ahz = fmaf(b.z, hv.z, ahz); ahz = fmaf(b.w, hv.w, ahz);
        ahn = fmaf(c.x, hv.x, ahn); ahn = fmaf(c.y, hv.y, ahn);
        ahn = fmaf(c.z, hv.z, ahn); ahn = fmaf(c.w, hv.w, ahn);
    }
    float sr   = wave_reduce_f(air + ahr);
    float sz   = wave_reduce_f(aiz + ahz);
    float sin_ = wave_reduce_f(ain);
    float shn  = wave_reduce_f(ahn);

    if (lane == 0) {
        float r = sigmoidf_(sr + bih[j] + bhh[j]);
        float z = sigmoidf_(sz + bih[H + j] + bhh[H + j]);
        float n = tanhf(sin_ + bih[2 * H + j] + r * (shn + bhh[2 * H + j]));
        hnxt[j] = (1.f - z) * n + z * hcur[j];
    }
}

__global__ void __launch_bounds__(NTHR)
seqae_fallback_kernel(Params p)
{
    cg::grid_group grid = cg::this_grid();
    const int lane = threadIdx.x & 63;
    const int wid  = blockIdx.x * (NTHR / 64) + (threadIdx.x >> 6);

    float* loss = p.ws;
    float* h0a  = p.ws + 64;
    float* h0b  = h0a + H;
    float* h1a  = h0b + H;
    float* h1b  = h1a + H;

    {
        int gtid = blockIdx.x * NTHR + threadIdx.x;
        if (gtid == 0) *loss = 0.f;
        for (int i = gtid; i < H; i += NBLK * NTHR) { h0a[i] = 0.f; h1a[i] = 0.f; }
    }
    grid.sync();

    const float* ebih0 = p.ebih;        const float* ebih1 = p.ebih + TH;
    const float* ebhh0 = p.ebhh;        const float* ebhh1 = p.ebhh + TH;
    const float* eWhh0 = p.eWhh;        const float* eWhh1 = p.eWhh + (size_t)TH * H;

    float* h0c = h0a; float* h0n = h0b;
    float* h1c = h1a; float* h1n = h1b;

    for (int t = 0; t < SEQLEN; ++t) {
        const float* x = p.seq + (size_t)t * NIN;
        gru_phase_fb<NIN>(wid, lane, p.eWih0, eWhh0, ebih0, ebhh0, x, h0c, h0n);
        grid.sync();
        gru_phase_fb<H>(wid, lane, p.eWih1, eWhh1, ebih1, ebhh1, h0n, h1c, h1n);
        grid.sync();
        float* tmp;
        tmp = h0c; h0c = h0n; h0n = tmp;
        tmp = h1c; h1c = h1n; h1n = tmp;
    }

    {
        int j = wid;
        float vj = h1c[j];
        int cnt = 0;
        for (int i = lane; i < H; i += 64) {
            float vi = h1c[i];
            cnt += (vi > vj) || (vi == vj && i < j);
        }
#pragma unroll
        for (int m = 32; m >= 1; m >>= 1) cnt += __shfl_xor(cnt, m, 64);
        if (lane == 0) h1n[j] = (cnt < KSP) ? vj : 0.f;
    }
    grid.sync();
    { float* tmp = h1c; h1c = h1n; h1n = tmp; }

    const float* dbih0 = p.dbih;        const float* dbih1 = p.dbih + TH;
    const float* dbhh0 = p.dbhh;        const float* dbhh1 = p.dbhh + TH;
    const float* dWhh0 = p.dWhh;        const float* dWhh1 = p.dWhh + (size_t)TH * H;

    float lsum = 0.f;
    for (int t = 0; t < SEQLEN - 1; ++t) {
        const float* x = (t == 0) ? (p.seq + (size_t)(SEQLEN - 1) * NIN)
                                  : (p.out + (size_t)(t - 1) * NIN);
        gru_phase_fb<NIN>(wid, lane, p.dWih0, dWhh0, dbih0, dbhh0, x, h0c, h0n);
        grid.sync();
        gru_phase_fb<H>(wid, lane, p.dWih1, dWhh1, dbih1, dbhh1, h0n, h1c, h1n);
        grid.sync();
        if (wid < NIN) {
            int j = wid;
            const float4* wo = (const float4*)(p.dWout + (size_t)j * H);
            const float4* h4 = (const float4*)h1n;
            float a = 0.f;
#pragma unroll
            for (int k = 0; k < H / 256; ++k) {
                int i = lane + 64 * k;
                float4 w = wo[i]; float4 hv = h4[i];
                a = fmaf(w.x, hv.x, a); a = fmaf(w.y, hv.y, a);
                a = fmaf(w.z, hv.z, a); a = fmaf(w.w, hv.w, a);
            }
            a = wave_reduce_f(a);
            if (lane == 0) {
                float o = a + p.dbout[j];
                p.out[(size_t)t * NIN + j] = o;
                float tg = p.seq[(size_t)(SEQLEN - 2 - t) * NIN + j];
                float d = o - tg;
                lsum = fmaf(d, d, lsum);
            }
        }
        grid.sync();
        float* tmp;
        tmp = h0c; h0c = h0n; h0n = tmp;
        tmp = h1c; h1c = h1n; h1n = tmp;
    }

    if (wid < NIN && lane == 0) atomicAdd(loss, lsum);
    grid.sync();
    if (blockIdx.x == 0 && threadIdx.x == 0) {
        p.out[(size_t)(SEQLEN - 1) * NIN] = (*loss) * (1.f / ((float)NIN * (float)SEQLEN));
    }
}

extern "C" void kernel_launch(void* const* d_in, const int* in_sizes, int n_in,
                              void* d_out, int out_size, void* d_ws, size_t ws_size,
                              hipStream_t stream)
{
    Params p;
    p.seq   = (const float*)d_in[0];
    p.eWih0 = (const float*)d_in[1];
    p.eWih1 = (const float*)d_in[2];
    p.eWhh  = (const float*)d_in[3];
    p.ebih  = (const float*)d_in[4];
    p.ebhh  = (const float*)d_in[5];
    p.dWih0 = (const float*)d_in[6];
    p.dWih1 = (const float*)d_in[7];
    p.dWhh  = (const float*)d_in[8];
    p.dbih  = (const float*)d_in[9];
    p.dbhh  = (const float*)d_in[10];
    p.dWout = (const float*)d_in[11];
    p.dbout = (const float*)d_in[12];
    p.out = (float*)d_out;
    p.ws  = (float*)d_ws;

    size_t need = WS_STATE_BYTES + (size_t)U_TOTAL * 4;
    if (ws_size >= need) {
        uint32* U = (uint32*)((char*)d_ws + WS_STATE_BYTES);
        const int PB = 256, PG = 1024;
        // encoder
        pack_kernel<<<PG, PB, 0, stream>>>(p.eWih0, U + O_EA, 1572864, NIN, 3);
        pack_kernel<<<PG, PB, 0, stream>>>(p.eWhh,  U + O_EB, 6291456, H, 3);
        pack_kernel<<<PG, PB, 0, stream>>>(p.eWih1, U + O_EC, 6291456, H, 3);
        pack_kernel<<<PG, PB, 0, stream>>>(p.eWhh + (size_t)TH * H, U + O_ED, 6291456, H, 3);
        // decoder
        pack_kernel<<<PG, PB, 0, stream>>>(p.dWih0, U + O_DA, 1572864, NIN, 3);
        pack_kernel<<<PG, PB, 0, stream>>>(p.dWhh,  U + O_DB, 6291456, H, 3);
        pack_kernel<<<PG, PB, 0, stream>>>(p.dWih1, U + O_DC, 6291456, H, 3);
        pack_kernel<<<PG, PB, 0, stream>>>(p.dWhh + (size_t)TH * H, U + O_DD, 6291456, H, 3);
        // output linear
        pack_kernel<<<PG, PB, 0, stream>>>(p.dWout, U + O_WO, 524288, H, 1);

        void* args[] = { &p };
        (void)hipLaunchCooperativeKernel((void*)seqae_reg_kernel, dim3(NBLK), dim3(NTHR),
                                         args, 0, stream);
    } else {
        void* args[] = { &p };
        (void)hipLaunchCooperativeKernel((void*)seqae_fallback_kernel, dim3(NBLK), dim3(NTHR),
                                         args, 0, stream);
    }
}